// Round 1
// baseline (419.575 us; speedup 1.0000x reference)
//
#include <hip/hip_runtime.h>

#define B_ROWS 32768
#define NIN 41
#define NL2 4
#define NRC 8

__device__ __forceinline__ float clampf(float v, float lo, float hi) {
    return fminf(fmaxf(v, lo), hi);
}

__device__ __forceinline__ float4 clamp4(float4 v) {
    v.x = clampf(v.x, -1.f, 1.f);
    v.y = clampf(v.y, -1.f, 1.f);
    v.z = clampf(v.z, -1.f, 1.f);
    v.w = clampf(v.w, -1.f, 1.f);
    return v;
}

// full 64-lane butterfly sum; all lanes receive the total
__device__ __forceinline__ float wave_sum(float v) {
    #pragma unroll
    for (int m = 1; m < 64; m <<= 1)
        v += __shfl_xor(v, m, 64);
    return v;
}

__global__ void __launch_bounds__(256) pgnet_kernel(
    const float* __restrict__ inp,
    const float* __restrict__ fpg_w,
    const float* __restrict__ fpg_b,
    const float* __restrict__ rpg_w,
    const float* __restrict__ rpg_b,
    const float* __restrict__ pgw,   // [8,86]
    const float* __restrict__ pgb,   // [8]
    float* __restrict__ out)
{
    const int lane = threadIdx.x & 63;
    const int row  = blockIdx.x * 4 + (threadIdx.x >> 6);
    const bool act = lane < NIN;
    const int  i   = lane;

    // ---- loads (all independent; issue up-front) ----
    const float x = act ? inp[row * NIN + i] : 0.0f;

    // fpg_w[b,o,i,r]: idx = b*1312 + o*328 + i*8 + r -> per lane 4x(2 float4)
    float4 fw[NL2][2];
    {
        const float* fb_ = fpg_w + (size_t)row * 1312;
        #pragma unroll
        for (int o = 0; o < NL2; ++o) {
            if (act) {
                fw[o][0] = clamp4(*(const float4*)(fb_ + o * 328 + i * 8));
                fw[o][1] = clamp4(*(const float4*)(fb_ + o * 328 + i * 8 + 4));
            } else {
                fw[o][0] = make_float4(0.f, 0.f, 0.f, 0.f);
                fw[o][1] = make_float4(0.f, 0.f, 0.f, 0.f);
            }
        }
    }

    // rpg_w[b,i,o,r]: idx = b*1312 + i*32 + o*8 + r -> 32 contiguous floats per lane
    float4 rw[8];
    {
        const float* rb_ = rpg_w + (size_t)row * 1312 + (size_t)i * 32;
        #pragma unroll
        for (int j = 0; j < 8; ++j)
            rw[j] = act ? clamp4(((const float4*)rb_)[j]) : make_float4(0.f, 0.f, 0.f, 0.f);
    }

    // pgctrl: rcin = [inp(0..40), l2old=0(41..44), inp-l1i(45..85)]
    // A[r] = pgb[r] + sum_i inp[i]*(W[r,i] + W[r,45+i]);  correction: sum_i l1i[i]*W[r,45+i]
    float W2[NRC];
    float A[NRC];
    #pragma unroll
    for (int r = 0; r < NRC; ++r) {
        const float w1 = act ? pgw[r * 86 + i] : 0.f;
        const float w2 = act ? pgw[r * 86 + 45 + i] : 0.f;
        W2[r] = w2;
        A[r]  = wave_sum(x * (w1 + w2)) + pgb[r];
    }

    float fb[NL2];
    #pragma unroll
    for (int o = 0; o < NL2; ++o) fb[o] = fpg_b[row * NL2 + o];
    const float rb = act ? rpg_b[row * NIN + i] : 0.f;

    // ---- 2 outer iterations, fully in registers ----
    float l1 = 0.0f;        // this lane's l1i[i]
    float rc[NRC];
    float l2[NL2];

    #pragma unroll
    for (int it = 0; it < 2; ++it) {
        // rc = leaky(A - sum_i l1i*W2); rc = clip(0.4*rc, -0.2, 1)
        #pragma unroll
        for (int r = 0; r < NRC; ++r) {
            const float corr = wave_sum(l1 * W2[r]);
            float v = A[r] - corr;
            v = (v >= 0.f) ? v : 0.2f * v;
            rc[r] = clampf(0.4f * v, -0.2f, 1.0f);
        }
        // 3x tridiagonal blur (0.8 diag, 0.1 off, edge-truncated)
        #pragma unroll
        for (int t = 0; t < 3; ++t) {
            float tmp[NRC];
            #pragma unroll
            for (int r = 0; r < NRC; ++r) {
                float v = 0.8f * rc[r];
                if (r > 0)        v += 0.1f * rc[r - 1];
                if (r < NRC - 1)  v += 0.1f * rc[r + 1];
                tmp[r] = v;
            }
            #pragma unroll
            for (int r = 0; r < NRC; ++r) rc[r] = tmp[r];
        }
        // l2[o] = clip(0.1*(sum_{i,r} fpg_w*rc*inp + fb[o]), -0.2, 1)
        #pragma unroll
        for (int o = 0; o < NL2; ++o) {
            const float d = fw[o][0].x * rc[0] + fw[o][0].y * rc[1]
                          + fw[o][0].z * rc[2] + fw[o][0].w * rc[3]
                          + fw[o][1].x * rc[4] + fw[o][1].y * rc[5]
                          + fw[o][1].z * rc[6] + fw[o][1].w * rc[7];
            const float s = wave_sum(x * d) + fb[o];
            l2[o] = clampf(0.1f * s, -0.2f, 1.0f);
        }
        // 2x blur on l2
        #pragma unroll
        for (int t = 0; t < 2; ++t) {
            float tmp[NL2];
            #pragma unroll
            for (int o = 0; o < NL2; ++o) {
                float v = 0.8f * l2[o];
                if (o > 0)        v += 0.1f * l2[o - 1];
                if (o < NL2 - 1)  v += 0.1f * l2[o + 1];
                tmp[o] = v;
            }
            #pragma unroll
            for (int o = 0; o < NL2; ++o) l2[o] = tmp[o];
        }
        // l1i[i] = clip(rb + sum_{o,r} rpg_w[i,o,r]*rc[r]*l2[o], -0.2, 1)
        float acc = rb;
        #pragma unroll
        for (int o = 0; o < NL2; ++o) {
            const float d = rw[2 * o].x * rc[0] + rw[2 * o].y * rc[1]
                          + rw[2 * o].z * rc[2] + rw[2 * o].w * rc[3]
                          + rw[2 * o + 1].x * rc[4] + rw[2 * o + 1].y * rc[5]
                          + rw[2 * o + 1].z * rc[6] + rw[2 * o + 1].w * rc[7];
            acc += l2[o] * d;
        }
        l1 = clampf(acc, -0.2f, 1.0f);   // lanes >= 41: rb=0, rw=0 -> l1=0
    }

    // ---- stores: [l1i (B*41) | l2 (B*4) | rc (B*8)] ----
    if (act) out[(size_t)row * NIN + i] = l1;
    if (lane < NL2) {
        float v = l2[0];
        #pragma unroll
        for (int o = 1; o < NL2; ++o) if (lane == o) v = l2[o];
        out[(size_t)B_ROWS * NIN + (size_t)row * NL2 + lane] = v;
    }
    if (lane < NRC) {
        float v = rc[0];
        #pragma unroll
        for (int r = 1; r < NRC; ++r) if (lane == r) v = rc[r];
        out[(size_t)B_ROWS * (NIN + NL2) + (size_t)row * NRC + lane] = v;
    }
}

extern "C" void kernel_launch(void* const* d_in, const int* in_sizes, int n_in,
                              void* d_out, int out_size, void* d_ws, size_t ws_size,
                              hipStream_t stream) {
    const float* inp   = (const float*)d_in[0];
    const float* fpg_w = (const float*)d_in[1];
    const float* fpg_b = (const float*)d_in[2];
    const float* rpg_w = (const float*)d_in[3];
    const float* rpg_b = (const float*)d_in[4];
    const float* pgw   = (const float*)d_in[5];
    const float* pgb   = (const float*)d_in[6];
    float* out = (float*)d_out;

    dim3 grid(B_ROWS / 4);   // one wave per row, 4 rows per 256-thread block
    dim3 block(256);
    hipLaunchKernelGGL(pgnet_kernel, grid, block, 0, stream,
                       inp, fpg_w, fpg_b, rpg_w, rpg_b, pgw, pgb, out);
}

// Round 2
// 401.737 us; speedup vs baseline: 1.0444x; 1.0444x over previous
//
#include <hip/hip_runtime.h>

#define B_ROWS 32768
#define NIN 41
#define NL2 4
#define NRC 8

__device__ __forceinline__ float clampf(float v, float lo, float hi) {
    return fminf(fmaxf(v, lo), hi);
}

__device__ __forceinline__ float clamp1(float v) {
    return fminf(fmaxf(v, -1.f), 1.f);
}

// one DPP step: x += dpp(x, ctrl); invalid/unsourced lanes contribute 0
template <int Ctrl>
__device__ __forceinline__ int dpp_add(int x) {
    return __float_as_int(
        __int_as_float(x) +
        __int_as_float(__builtin_amdgcn_update_dpp(0, x, Ctrl, 0xf, 0xf, true)));
}

// full 64-lane sum via DPP (VALU pipe only), result wave-uniform (SGPR)
__device__ __forceinline__ float wave_sum_uniform(float v) {
    int x = __float_as_int(v);
    x = dpp_add<0x111>(x);  // row_shr:1
    x = dpp_add<0x112>(x);  // row_shr:2
    x = dpp_add<0x114>(x);  // row_shr:4
    x = dpp_add<0x118>(x);  // row_shr:8  -> lane 15/31/47/63 hold row sums
    x = dpp_add<0x142>(x);  // row_bcast:15 -> lane 31 = rows0+1, lane 63 = rows2+3
    x = dpp_add<0x143>(x);  // row_bcast:31 -> lane 63 = total
    return __int_as_float(__builtin_amdgcn_readlane(x, 63));
}

__global__ void __launch_bounds__(256) pgnet_kernel(
    const float* __restrict__ inp,
    const float* __restrict__ fpg_w,
    const float* __restrict__ fpg_b,
    const float* __restrict__ rpg_w,
    const float* __restrict__ rpg_b,
    const float* __restrict__ pgw,   // [8,86]
    const float* __restrict__ pgb,   // [8]
    float* __restrict__ out)
{
    const int lane = threadIdx.x & 63;
    const int row  = blockIdx.x * 4 + (threadIdx.x >> 6);
    const bool act = lane < NIN;

    // ---------- per-lane loads ----------
    const float x = act ? inp[row * NIN + lane] : 0.0f;

    // fpg_w[b,o,i,r]: b*1312 + o*328 + i*8 + r  (8 contiguous floats per (o,i))
    float fw[NL2][NRC];
    {
        const float* fp = fpg_w + (size_t)row * 1312 + (size_t)lane * 8;
        #pragma unroll
        for (int o = 0; o < NL2; ++o) {
            float4 t0 = act ? *(const float4*)(fp + o * 328)     : make_float4(0,0,0,0);
            float4 t1 = act ? *(const float4*)(fp + o * 328 + 4) : make_float4(0,0,0,0);
            fw[o][0] = clamp1(t0.x); fw[o][1] = clamp1(t0.y);
            fw[o][2] = clamp1(t0.z); fw[o][3] = clamp1(t0.w);
            fw[o][4] = clamp1(t1.x); fw[o][5] = clamp1(t1.y);
            fw[o][6] = clamp1(t1.z); fw[o][7] = clamp1(t1.w);
        }
    }

    // rpg_w[b,i,o,r]: b*1312 + i*32 + o*8 + r  (32 contiguous floats per i)
    float rw[NL2][NRC];
    {
        const float* rp = rpg_w + (size_t)row * 1312 + (size_t)lane * 32;
        #pragma unroll
        for (int o = 0; o < NL2; ++o) {
            float4 t0 = act ? ((const float4*)rp)[2 * o]     : make_float4(0,0,0,0);
            float4 t1 = act ? ((const float4*)rp)[2 * o + 1] : make_float4(0,0,0,0);
            rw[o][0] = clamp1(t0.x); rw[o][1] = clamp1(t0.y);
            rw[o][2] = clamp1(t0.z); rw[o][3] = clamp1(t0.w);
            rw[o][4] = clamp1(t1.x); rw[o][5] = clamp1(t1.y);
            rw[o][6] = clamp1(t1.z); rw[o][7] = clamp1(t1.w);
        }
    }

    // pgctrl weights: rcin = [inp(0..40), l2old=0(41..44), inp-l1i(45..85)]
    float W2[NRC];   // per-lane W[r, 45+i]
    float A[NRC];    // uniform: pgb[r] + sum_i x_i*(W[r,i]+W[r,45+i])
    #pragma unroll
    for (int r = 0; r < NRC; ++r) {
        const float w1 = act ? pgw[r * 86 + lane]      : 0.f;
        const float w2 = act ? pgw[r * 86 + 45 + lane] : 0.f;
        W2[r] = w2;
        A[r]  = wave_sum_uniform(x * (w1 + w2)) + pgb[r];
    }

    // F[o][r] = sum_i x_i * clip(fpg_w)[o,i,r]  — iteration-invariant, uniform
    float F[NL2][NRC];
    #pragma unroll
    for (int o = 0; o < NL2; ++o)
        #pragma unroll
        for (int r = 0; r < NRC; ++r)
            F[o][r] = wave_sum_uniform(x * fw[o][r]);
    // fw is dead from here on

    float fb[NL2];
    #pragma unroll
    for (int o = 0; o < NL2; ++o) fb[o] = fpg_b[row * NL2 + o];
    const float rb = act ? rpg_b[row * NIN + lane] : 0.f;

    // ---------- 2 outer iterations ----------
    float l1 = 0.0f;           // per-lane l1i[i]
    float rcv[NRC], l2v[NL2];  // wave-uniform

    #pragma unroll
    for (int it = 0; it < 2; ++it) {
        #pragma unroll
        for (int r = 0; r < NRC; ++r) {
            float pre = A[r];
            if (it > 0) pre -= wave_sum_uniform(l1 * W2[r]);  // iter 0: l1i == 0
            float v = (pre >= 0.f) ? pre : 0.2f * pre;        // LeakyReLU(0.2)
            rcv[r] = clampf(0.4f * v, -0.2f, 1.0f);           // rcold == 0
        }
        // 3x tridiagonal blur (0.8 diag, 0.1 off, edge-truncated)
        #pragma unroll
        for (int t = 0; t < 3; ++t) {
            float tmp[NRC];
            #pragma unroll
            for (int r = 0; r < NRC; ++r) {
                float v = 0.8f * rcv[r];
                if (r > 0)       v += 0.1f * rcv[r - 1];
                if (r < NRC - 1) v += 0.1f * rcv[r + 1];
                tmp[r] = v;
            }
            #pragma unroll
            for (int r = 0; r < NRC; ++r) rcv[r] = tmp[r];
        }
        // l2[o] = clip(0.1*(sum_r F[o,r]*rc[r] + fb[o]), -0.2, 1)  — uniform math
        #pragma unroll
        for (int o = 0; o < NL2; ++o) {
            float s = fb[o];
            #pragma unroll
            for (int r = 0; r < NRC; ++r) s += F[o][r] * rcv[r];
            l2v[o] = clampf(0.1f * s, -0.2f, 1.0f);
        }
        // 2x blur on l2
        #pragma unroll
        for (int t = 0; t < 2; ++t) {
            float tmp[NL2];
            #pragma unroll
            for (int o = 0; o < NL2; ++o) {
                float v = 0.8f * l2v[o];
                if (o > 0)       v += 0.1f * l2v[o - 1];
                if (o < NL2 - 1) v += 0.1f * l2v[o + 1];
                tmp[o] = v;
            }
            #pragma unroll
            for (int o = 0; o < NL2; ++o) l2v[o] = tmp[o];
        }
        // l1i[i] = clip(rb + sum_o l2[o] * (sum_r rw[i,o,r]*rc[r]), -0.2, 1)
        float acc = rb;
        #pragma unroll
        for (int o = 0; o < NL2; ++o) {
            float d = 0.f;
            #pragma unroll
            for (int r = 0; r < NRC; ++r) d += rw[o][r] * rcv[r];
            acc += l2v[o] * d;
        }
        l1 = clampf(acc, -0.2f, 1.0f);  // inactive lanes: rb=0, rw=0 -> 0
    }

    // ---------- stores: [l1i (B*41) | l2 (B*4) | rc (B*8)] ----------
    if (act) out[(size_t)row * NIN + lane] = l1;
    if (lane < NL2) {
        float v = l2v[0];
        #pragma unroll
        for (int o = 1; o < NL2; ++o) if (lane == o) v = l2v[o];
        out[(size_t)B_ROWS * NIN + (size_t)row * NL2 + lane] = v;
    }
    if (lane < NRC) {
        float v = rcv[0];
        #pragma unroll
        for (int r = 1; r < NRC; ++r) if (lane == r) v = rcv[r];
        out[(size_t)B_ROWS * (NIN + NL2) + (size_t)row * NRC + lane] = v;
    }
}

extern "C" void kernel_launch(void* const* d_in, const int* in_sizes, int n_in,
                              void* d_out, int out_size, void* d_ws, size_t ws_size,
                              hipStream_t stream) {
    const float* inp   = (const float*)d_in[0];
    const float* fpg_w = (const float*)d_in[1];
    const float* fpg_b = (const float*)d_in[2];
    const float* rpg_w = (const float*)d_in[3];
    const float* rpg_b = (const float*)d_in[4];
    const float* pgw   = (const float*)d_in[5];
    const float* pgb   = (const float*)d_in[6];
    float* out = (float*)d_out;

    dim3 grid(B_ROWS / 4);   // one wave per row
    dim3 block(256);
    hipLaunchKernelGGL(pgnet_kernel, grid, block, 0, stream,
                       inp, fpg_w, fpg_b, rpg_w, rpg_b, pgw, pgb, out);
}

// Round 3
// 360.584 us; speedup vs baseline: 1.1636x; 1.1141x over previous
//
#include <hip/hip_runtime.h>

#define B_ROWS 32768
#define NIN 41
#define NL2 4
#define NRC 8

__device__ __forceinline__ float clampf(float v, float lo, float hi) {
    return fminf(fmaxf(v, lo), hi);
}

__device__ __forceinline__ float clamp1(float v) {
    return fminf(fmaxf(v, -1.f), 1.f);
}

// one DPP step: x += dpp(x, ctrl)
template <int Ctrl>
__device__ __forceinline__ int dpp_add(int x) {
    return __float_as_int(
        __int_as_float(x) +
        __int_as_float(__builtin_amdgcn_update_dpp(0, x, Ctrl, 0xf, 0xf, true)));
}

// full 64-lane sum via DPP (VALU pipe only), result wave-uniform (SGPR)
__device__ __forceinline__ float wave_sum_uniform(float v) {
    int x = __float_as_int(v);
    x = dpp_add<0x111>(x);  // row_shr:1
    x = dpp_add<0x112>(x);  // row_shr:2
    x = dpp_add<0x114>(x);  // row_shr:4
    x = dpp_add<0x118>(x);  // row_shr:8  -> lanes 15/31/47/63 hold row sums
    x = dpp_add<0x142>(x);  // row_bcast:15
    x = dpp_add<0x143>(x);  // row_bcast:31 -> lane 63 = total
    return __int_as_float(__builtin_amdgcn_readlane(x, 63));
}

__global__ void __launch_bounds__(256, 4) pgnet_kernel(
    const float* __restrict__ inp,
    const float* __restrict__ fpg_w,
    const float* __restrict__ fpg_b,
    const float* __restrict__ rpg_w,
    const float* __restrict__ rpg_b,
    const float* __restrict__ pgw,   // [8,86]
    const float* __restrict__ pgb,   // [8]
    float* __restrict__ out)
{
    const int lane = threadIdx.x & 63;
    const int row  = blockIdx.x * 4 + (threadIdx.x >> 6);
    const bool act = lane < NIN;
    const int safe = act ? lane : (NIN - 1);   // in-bounds address for all lanes

    // ================= load block: issue EVERYTHING, no branches =================
    const float x_raw = inp[row * NIN + safe];

    // fpg_w[b,o,i,r]: b*1312 + o*328 + i*8 + r  (8 contiguous floats per (o,i))
    const float* fp = fpg_w + (size_t)row * 1312 + (size_t)safe * 8;
    float4 fwv[NL2][2];
    #pragma unroll
    for (int o = 0; o < NL2; ++o) {
        fwv[o][0] = *(const float4*)(fp + o * 328);
        fwv[o][1] = *(const float4*)(fp + o * 328 + 4);
    }

    // rpg_w[b,i,o,r]: b*1312 + i*32 + o*8 + r  (32 contiguous floats per i)
    const float* rp = rpg_w + (size_t)row * 1312 + (size_t)safe * 32;
    float4 rwv[8];
    #pragma unroll
    for (int j = 0; j < 8; ++j) rwv[j] = ((const float4*)rp)[j];

    // pgctrl table (688 B, L1-resident after first waves)
    float w1r[NRC], w2r[NRC];
    #pragma unroll
    for (int r = 0; r < NRC; ++r) {
        w1r[r] = pgw[r * 86 + safe];
        w2r[r] = pgw[r * 86 + 45 + safe];
    }

    const float4 fbv  = *(const float4*)(fpg_b + (size_t)row * NL2); // uniform per wave
    const float  rb_r = rpg_b[row * NIN + safe];

    __builtin_amdgcn_sched_barrier(0);   // keep all loads issued before any math
    // =============================================================================

    const float x  = act ? x_raw : 0.0f;   // zeroing x kills junk-lane fw contributions
    const float rb = act ? rb_r  : 0.0f;

    float fw[NL2][NRC];
    #pragma unroll
    for (int o = 0; o < NL2; ++o) {
        fw[o][0] = clamp1(fwv[o][0].x); fw[o][1] = clamp1(fwv[o][0].y);
        fw[o][2] = clamp1(fwv[o][0].z); fw[o][3] = clamp1(fwv[o][0].w);
        fw[o][4] = clamp1(fwv[o][1].x); fw[o][5] = clamp1(fwv[o][1].y);
        fw[o][6] = clamp1(fwv[o][1].z); fw[o][7] = clamp1(fwv[o][1].w);
    }
    float rw[NL2][NRC];
    #pragma unroll
    for (int o = 0; o < NL2; ++o) {
        rw[o][0] = clamp1(rwv[2*o].x);   rw[o][1] = clamp1(rwv[2*o].y);
        rw[o][2] = clamp1(rwv[2*o].z);   rw[o][3] = clamp1(rwv[2*o].w);
        rw[o][4] = clamp1(rwv[2*o+1].x); rw[o][5] = clamp1(rwv[2*o+1].y);
        rw[o][6] = clamp1(rwv[2*o+1].z); rw[o][7] = clamp1(rwv[2*o+1].w);
    }

    // A[r] = pgb[r] + sum_i x_i*(W[r,i]+W[r,45+i]); W2 zeroed on junk lanes for corr
    float W2[NRC], A[NRC];
    #pragma unroll
    for (int r = 0; r < NRC; ++r) {
        W2[r] = act ? w2r[r] : 0.0f;
        A[r]  = wave_sum_uniform(x * (w1r[r] + w2r[r])) + pgb[r];
    }

    // F[o][r] = sum_i x_i * clip(fpg_w)[o,i,r] — iteration-invariant, wave-uniform
    float F[NL2][NRC];
    #pragma unroll
    for (int o = 0; o < NL2; ++o)
        #pragma unroll
        for (int r = 0; r < NRC; ++r)
            F[o][r] = wave_sum_uniform(x * fw[o][r]);
    // fw dead from here

    const float fb[NL2] = {fbv.x, fbv.y, fbv.z, fbv.w};

    // ---------- 2 outer iterations ----------
    float l1 = 0.0f;
    float rcv[NRC], l2v[NL2];

    #pragma unroll
    for (int it = 0; it < 2; ++it) {
        #pragma unroll
        for (int r = 0; r < NRC; ++r) {
            float pre = A[r];
            if (it > 0) pre -= wave_sum_uniform(l1 * W2[r]);  // iter 0: l1i == 0
            float v = (pre >= 0.f) ? pre : 0.2f * pre;        // LeakyReLU(0.2)
            rcv[r] = clampf(0.4f * v, -0.2f, 1.0f);
        }
        #pragma unroll
        for (int t = 0; t < 3; ++t) {   // 3x tridiagonal blur
            float tmp[NRC];
            #pragma unroll
            for (int r = 0; r < NRC; ++r) {
                float v = 0.8f * rcv[r];
                if (r > 0)       v += 0.1f * rcv[r - 1];
                if (r < NRC - 1) v += 0.1f * rcv[r + 1];
                tmp[r] = v;
            }
            #pragma unroll
            for (int r = 0; r < NRC; ++r) rcv[r] = tmp[r];
        }
        #pragma unroll
        for (int o = 0; o < NL2; ++o) {
            float s = fb[o];
            #pragma unroll
            for (int r = 0; r < NRC; ++r) s += F[o][r] * rcv[r];
            l2v[o] = clampf(0.1f * s, -0.2f, 1.0f);
        }
        #pragma unroll
        for (int t = 0; t < 2; ++t) {   // 2x blur on l2
            float tmp[NL2];
            #pragma unroll
            for (int o = 0; o < NL2; ++o) {
                float v = 0.8f * l2v[o];
                if (o > 0)       v += 0.1f * l2v[o - 1];
                if (o < NL2 - 1) v += 0.1f * l2v[o + 1];
                tmp[o] = v;
            }
            #pragma unroll
            for (int o = 0; o < NL2; ++o) l2v[o] = tmp[o];
        }
        float acc = rb;
        #pragma unroll
        for (int o = 0; o < NL2; ++o) {
            float d = 0.f;
            #pragma unroll
            for (int r = 0; r < NRC; ++r) d += rw[o][r] * rcv[r];
            acc += l2v[o] * d;
        }
        l1 = clampf(acc, -0.2f, 1.0f);  // junk lanes only feed corr via W2=0
    }

    // ---------- stores: [l1i (B*41) | l2 (B*4) | rc (B*8)] ----------
    if (act) out[(size_t)row * NIN + lane] = l1;
    if (lane < NL2) {
        float v = l2v[0];
        #pragma unroll
        for (int o = 1; o < NL2; ++o) if (lane == o) v = l2v[o];
        out[(size_t)B_ROWS * NIN + (size_t)row * NL2 + lane] = v;
    }
    if (lane < NRC) {
        float v = rcv[0];
        #pragma unroll
        for (int r = 1; r < NRC; ++r) if (lane == r) v = rcv[r];
        out[(size_t)B_ROWS * (NIN + NL2) + (size_t)row * NRC + lane] = v;
    }
}

extern "C" void kernel_launch(void* const* d_in, const int* in_sizes, int n_in,
                              void* d_out, int out_size, void* d_ws, size_t ws_size,
                              hipStream_t stream) {
    const float* inp   = (const float*)d_in[0];
    const float* fpg_w = (const float*)d_in[1];
    const float* fpg_b = (const float*)d_in[2];
    const float* rpg_w = (const float*)d_in[3];
    const float* rpg_b = (const float*)d_in[4];
    const float* pgw   = (const float*)d_in[5];
    const float* pgb   = (const float*)d_in[6];
    float* out = (float*)d_out;

    dim3 grid(B_ROWS / 4);   // one wave per row
    dim3 block(256);
    hipLaunchKernelGGL(pgnet_kernel, grid, block, 0, stream,
                       inp, fpg_w, fpg_b, rpg_w, rpg_b, pgw, pgb, out);
}